// Round 8
// baseline (291.349 us; speedup 1.0000x reference)
//
#include <hip/hip_runtime.h>
#include <stdint.h>

#define B 64
#define H 384
#define W 512
#define NPX (H*W)            // 196608
#define TRIM_IDX 157286      // int(0.8 * 196608)
#define RPW 8                // rows per wave in loss kernel

#define NB1 2048             // stage1 bins (11 bits)
#define CAPMAX 32768

// ---- workspace layout (uint32 units) ----
#define HIST_OFF 0
#define HIST_U32 (2*B*NB1)               // 262144 u32 = 1 MB
#define ACC_OFF  (HIST_OFF + HIST_U32)
#define N_OFF    (ACC_OFF + 0)           // [B]  u32 mask count (targ>0)
#define MS_OFF   (ACC_OFF + 64)          // [3][B] u32 subsample mask counts
#define TS_OFF   (ACC_OFF + 256)         // [B]  f32 tmae sum
#define GS_OFF   (ACC_OFF + 320)         // [4][B] f32 grad sums
#define TSUM_OFF (ACC_OFF + 576)         // [2][B] f32 total masked value sum
#define SB_OFF   (ACC_OFF + 704)         // [2][B] f32 sum of masked values < med
#define IDX_OFF  (ACC_OFF + 832)         // [2][B] u32 append counters
#define ZERO_U32 (HIST_U32 + 960)        // zero [0, ZERO_U32) at launch
// persistent (written before read each launch, not zeroed)
#define K_OFF    (ACC_OFF + 960)         // [2][B] u32 rank (k1 then k3)
#define PFX_OFF  (ACC_OFF + 1088)        // [2][B] u32 stage-1 bin (11 bits)
#define EQ_OFF   (ACC_OFF + 1216)        // [2][B] u32 count equal to median
#define SH_OFF   (ACC_OFF + 1344)        // [2][B] f32 median (shift)
#define RS_OFF   (ACC_OFF + 1472)        // [2][B] f32 reciprocal scale
#define THR_OFF  (ACC_OFF + 1600)        // [B]  f32 trim threshold
#define C2_OFF   (ACC_OFF + 1664)        // [B]  u32 count targ>shift_t
#define CNT1_OFF (ACC_OFF + 1728)        // [2][B] u32 stage-1 selected bin size
#define FIX_U32  (HIST_U32 + 1856)
#define BUF_OFF  (ACC_OFF + 1856)        // [2][B][cap] f32 candidate values

__device__ __forceinline__ uint32_t fmap(float f) {
    uint32_t b = __float_as_uint(f);
    return (b & 0x80000000u) ? ~b : (b | 0x80000000u);
}
__device__ __forceinline__ float funmap(uint32_t u) {
    uint32_t b = (u & 0x80000000u) ? (u & 0x7fffffffu) : ~u;
    return __uint_as_float(b);
}

// ---------------- stage 1: 11-bit histogram + n + total sums ----------------
// grid (32,B) x 256 thr; ALL 12 float4 loads hoisted (one latency, full MLP)
__global__ void __launch_bounds__(256) hist1_kernel(const float* __restrict__ pred,
                                                    const float* __restrict__ targ,
                                                    uint32_t* __restrict__ ws) {
    __shared__ uint32_t lh[2 * NB1];
    const int b = blockIdx.y;
    for (int i = threadIdx.x; i < 2 * NB1; i += 256) lh[i] = 0;
    __syncthreads();
    const float4* pb = (const float4*)(pred + (size_t)b * NPX);
    const float4* tb = (const float4*)(targ + (size_t)b * NPX);
    const int tid = blockIdx.x * 256 + threadIdx.x;
    float4 tv[6], pv[6];
    #pragma unroll
    for (int c = 0; c < 6; c++) { tv[c] = tb[tid + c * 8192]; pv[c] = pb[tid + c * 8192]; }
    uint32_t nloc = 0;
    float sump = 0.f, sumt = 0.f;
    #pragma unroll
    for (int c = 0; c < 6; c++) {
        float tA[4] = {tv[c].x, tv[c].y, tv[c].z, tv[c].w};
        float pA[4] = {pv[c].x, pv[c].y, pv[c].z, pv[c].w};
        #pragma unroll
        for (int k = 0; k < 4; k++) {
            float t = tA[k];
            if (t > 0.f) {
                float p = pA[k];
                nloc++; sumt += t; sump += p;
                atomicAdd(&lh[fmap(p) >> 21], 1u);
                atomicAdd(&lh[NB1 + (fmap(t) >> 21)], 1u);
            }
        }
    }
    __syncthreads();
    uint32_t* hist = ws + HIST_OFF;
    for (int i = threadIdx.x; i < 2 * NB1; i += 256) {
        uint32_t v = lh[i];
        if (v) {
            int which = i >> 11, bin = i & (NB1 - 1);
            atomicAdd(&hist[(size_t)(which * B + b) * NB1 + bin], v);
        }
    }
    for (int off = 32; off; off >>= 1) {
        nloc += __shfl_down(nloc, off, 64);
        sump += __shfl_down(sump, off, 64);
        sumt += __shfl_down(sumt, off, 64);
    }
    if ((threadIdx.x & 63) == 0) {
        if (nloc) atomicAdd(ws + N_OFF + b, nloc);
        atomicAdd(((float*)(ws + TSUM_OFF)) + b, sump);
        atomicAdd(((float*)(ws + TSUM_OFF)) + B + b, sumt);
    }
}

// ---------------- select stage 1 ----------------
__global__ void select1_kernel(uint32_t* __restrict__ ws) {
    const int b = blockIdx.x, which = blockIdx.y;
    const uint32_t* h = ws + HIST_OFF + (size_t)(which * B + b) * NB1;
    const uint32_t k = (ws[N_OFF + b] - 1u) >> 1;
    const int t = threadIdx.x;
    uint32_t mysum = 0;
    #pragma unroll
    for (int i = 0; i < 8; i++) mysum += h[t * 8 + i];
    __shared__ uint32_t s[256];
    s[t] = mysum;
    __syncthreads();
    for (int off = 1; off < 256; off <<= 1) {
        uint32_t add = (t >= off) ? s[t - off] : 0u;
        __syncthreads();
        s[t] += add;
        __syncthreads();
    }
    uint32_t incl = s[t], excl = incl - mysum;
    if (k >= excl && k < incl) {
        uint32_t c = excl, bin = 0, newk = 0, e = 0;
        for (int i = 0; i < 8; i++) {
            uint32_t hv = h[t * 8 + i];
            if (k < c + hv) { bin = t * 8 + i; newk = k - c; e = hv; break; }
            c += hv;
        }
        ws[PFX_OFF + which * B + b] = bin;
        ws[K_OFF + which * B + b] = newk;      // k1: rank within selected bin
        ws[CNT1_OFF + which * B + b] = e;      // bin size
    }
}

// ---------------- pass 2: sum-below-group + collect candidates ----------------
// grid (64,B) x 256 thr; wave-ballot compaction into LDS (no per-element atomics)
__global__ void __launch_bounds__(256) collect2_kernel(const float* __restrict__ pred,
                                                       const float* __restrict__ targ,
                                                       uint32_t* __restrict__ ws, int cap) {
    __shared__ float bp[3072], bt[3072];
    __shared__ uint32_t cp, ct, basep, baset;
    const int b = blockIdx.y;
    const int lane = threadIdx.x & 63;
    const unsigned long long lmask = (1ull << lane) - 1ull;
    if (threadIdx.x == 0) { cp = 0; ct = 0; }
    const uint32_t pfxp = ws[PFX_OFF + b];
    const uint32_t pfxt = ws[PFX_OFF + B + b];
    const bool dop = cap > 0 && ws[CNT1_OFF + b] <= (uint32_t)cap;
    const bool dot = cap > 0 && ws[CNT1_OFF + B + b] <= (uint32_t)cap;
    const float4* pb = (const float4*)(pred + (size_t)b * NPX);
    const float4* tb = (const float4*)(targ + (size_t)b * NPX);
    const int tid = blockIdx.x * 256 + threadIdx.x;
    float4 tv[3], pv[3];
    #pragma unroll
    for (int it = 0; it < 3; it++) { tv[it] = tb[tid + it * 16384]; pv[it] = pb[tid + it * 16384]; }
    __syncthreads();
    float sbp = 0.f, sbt = 0.f;
    #pragma unroll
    for (int it = 0; it < 3; it++) {
        float tA[4] = {tv[it].x, tv[it].y, tv[it].z, tv[it].w};
        float pA[4] = {pv[it].x, pv[it].y, pv[it].z, pv[it].w};
        #pragma unroll
        for (int k = 0; k < 4; k++) {
            float t = tA[k], p = pA[k];
            bool msk = t > 0.f;
            uint32_t u1p = fmap(p) >> 21, u1t = fmap(t) >> 21;
            if (msk && u1p < pfxp) sbp += p;
            if (msk && u1t < pfxt) sbt += t;
            // wave-aggregated append: one LDS atomic per wave-step, only if any match
            bool cnp = msk && u1p == pfxp && dop;
            unsigned long long bal = __ballot(cnp);
            if (bal) {
                int leader = __ffsll((long long)bal) - 1;
                uint32_t base = 0;
                if (lane == leader) base = atomicAdd(&cp, (uint32_t)__popcll(bal));
                base = (uint32_t)__shfl((int)base, leader, 64);
                if (cnp) bp[base + (uint32_t)__popcll(bal & lmask)] = p;
            }
            bool cnt_ = msk && u1t == pfxt && dot;
            bal = __ballot(cnt_);
            if (bal) {
                int leader = __ffsll((long long)bal) - 1;
                uint32_t base = 0;
                if (lane == leader) base = atomicAdd(&ct, (uint32_t)__popcll(bal));
                base = (uint32_t)__shfl((int)base, leader, 64);
                if (cnt_) bt[base + (uint32_t)__popcll(bal & lmask)] = t;
            }
        }
    }
    for (int off = 32; off; off >>= 1) {
        sbp += __shfl_down(sbp, off, 64);
        sbt += __shfl_down(sbt, off, 64);
    }
    if ((threadIdx.x & 63) == 0) {
        atomicAdd(((float*)(ws + SB_OFF)) + b, sbp);
        atomicAdd(((float*)(ws + SB_OFF)) + B + b, sbt);
    }
    __syncthreads();
    if (threadIdx.x == 0 && cp) basep = atomicAdd(ws + IDX_OFF + b, cp);
    if (threadIdx.x == 1 && ct) baset = atomicAdd(ws + IDX_OFF + B + b, ct);
    __syncthreads();
    float* bufp = ((float*)(ws + BUF_OFF)) + (size_t)b * cap;
    float* buft = ((float*)(ws + BUF_OFF)) + ((size_t)B + b) * cap;
    for (uint32_t i = threadIdx.x; i < cp; i += 256) bufp[basep + i] = bp[i];
    for (uint32_t i = threadIdx.x; i < ct; i += 256) buft[baset + i] = bt[i];
}

// ---------------- small select: finish remaining 21 bits from buffer ----------------
__global__ void small3_kernel(const float* __restrict__ pred,
                              const float* __restrict__ targ,
                              uint32_t* __restrict__ ws, int cap) {
    const int b = blockIdx.x, which = blockIdx.y;
    const int t = threadIdx.x;
    __shared__ uint32_t cnt[2048];
    __shared__ float fsm[2048];
    __shared__ uint32_t sc[256];
    __shared__ float sfl[256];
    __shared__ uint32_t r_bin, r_k;
    __shared__ float r_f;
    const uint32_t pfx1 = ws[PFX_OFF + which * B + b];
    const uint32_t k1 = ws[K_OFF + which * B + b];
    const uint32_t C = ws[CNT1_OFF + which * B + b];
    const bool fast = (cap > 0) && (C <= (uint32_t)cap);
    const float* buf = ((const float*)(ws + BUF_OFF)) + ((size_t)which * B + b) * (size_t)cap;
    const float* Tp = targ + (size_t)b * NPX;
    const float* Pp = pred + (size_t)b * NPX;

    // ---- pass A: mid 11 bits ----
    for (int i = t; i < 2048; i += 256) { cnt[i] = 0; fsm[i] = 0.f; }
    __syncthreads();
    if (fast) {
        for (uint32_t j = t; j < C; j += 256) {
            float v = buf[j];
            uint32_t u = fmap(v), mb = (u >> 10) & 2047u;
            atomicAdd(&cnt[mb], 1u); atomicAdd(&fsm[mb], v);
        }
    } else {
        for (int j = t; j < NPX; j += 256) {
            float tvv = Tp[j];
            if (tvv > 0.f) {
                float v = (which == 0) ? Pp[j] : tvv;
                uint32_t u = fmap(v);
                if ((u >> 21) == pfx1) {
                    uint32_t mb = (u >> 10) & 2047u;
                    atomicAdd(&cnt[mb], 1u); atomicAdd(&fsm[mb], v);
                }
            }
        }
    }
    __syncthreads();
    {
        uint32_t ms = 0; float mf = 0.f;
        #pragma unroll
        for (int i = 0; i < 8; i++) { ms += cnt[t * 8 + i]; mf += fsm[t * 8 + i]; }
        sc[t] = ms; sfl[t] = mf;
        __syncthreads();
        for (int off = 1; off < 256; off <<= 1) {
            uint32_t a = (t >= off) ? sc[t - off] : 0u;
            float af = (t >= off) ? sfl[t - off] : 0.f;
            __syncthreads();
            sc[t] += a; sfl[t] += af;
            __syncthreads();
        }
        uint32_t incl = sc[t], excl = incl - ms;
        float fx = sfl[t] - mf;
        if (k1 >= excl && k1 < incl) {
            uint32_t c = excl, bin = 0, nk = 0; float f = fx;
            for (int i = 0; i < 8; i++) {
                uint32_t hv = cnt[t * 8 + i];
                if (k1 < c + hv) { bin = t * 8 + i; nk = k1 - c; break; }
                c += hv; f += fsm[t * 8 + i];
            }
            r_bin = bin; r_k = nk; r_f = f;
        }
    }
    __syncthreads();
    const uint32_t mid_sel = r_bin, k2 = r_k;
    const float fbelowA = r_f;
    __syncthreads();
    // ---- pass B: low 10 bits ----
    for (int i = t; i < 1024; i += 256) { cnt[i] = 0; fsm[i] = 0.f; }
    __syncthreads();
    if (fast) {
        for (uint32_t j = t; j < C; j += 256) {
            float v = buf[j];
            uint32_t u = fmap(v);
            if (((u >> 10) & 2047u) == mid_sel) {
                uint32_t lb = u & 1023u;
                atomicAdd(&cnt[lb], 1u); atomicAdd(&fsm[lb], v);
            }
        }
    } else {
        for (int j = t; j < NPX; j += 256) {
            float tvv = Tp[j];
            if (tvv > 0.f) {
                float v = (which == 0) ? Pp[j] : tvv;
                uint32_t u = fmap(v);
                if ((u >> 21) == pfx1 && ((u >> 10) & 2047u) == mid_sel) {
                    uint32_t lb = u & 1023u;
                    atomicAdd(&cnt[lb], 1u); atomicAdd(&fsm[lb], v);
                }
            }
        }
    }
    __syncthreads();
    {
        uint32_t ms = 0; float mf = 0.f;
        #pragma unroll
        for (int i = 0; i < 4; i++) { ms += cnt[t * 4 + i]; mf += fsm[t * 4 + i]; }
        sc[t] = ms; sfl[t] = mf;
        __syncthreads();
        for (int off = 1; off < 256; off <<= 1) {
            uint32_t a = (t >= off) ? sc[t - off] : 0u;
            float af = (t >= off) ? sfl[t - off] : 0.f;
            __syncthreads();
            sc[t] += a; sfl[t] += af;
            __syncthreads();
        }
        uint32_t incl = sc[t], excl = incl - ms;
        float fx = sfl[t] - mf;
        if (k2 >= excl && k2 < incl) {
            uint32_t c = excl, bin = 0, nk = 0, e = 0; float f = fx;
            for (int i = 0; i < 4; i++) {
                uint32_t hv = cnt[t * 4 + i];
                if (k2 < c + hv) { bin = t * 4 + i; nk = k2 - c; e = hv; break; }
                c += hv; f += fsm[t * 4 + i];
            }
            uint32_t u = (pfx1 << 21) | (mid_sel << 10) | bin;
            ((float*)(ws + SH_OFF))[which * B + b] = funmap(u);
            ws[K_OFF + which * B + b] = nk;      // k3
            ws[EQ_OFF + which * B + b] = e;
            ((float*)(ws + SB_OFF))[which * B + b] += fbelowA + f;
        }
    }
}

// ---------------- params: scales from sum decomposition, c2, trim threshold ----------------
__global__ void param_kernel(const float* __restrict__ pred,
                             const float* __restrict__ targ,
                             uint32_t* __restrict__ ws) {
    const int b = threadIdx.x;
    if (b >= B) return;
    const uint32_t n = ws[N_OFF + b];
    const uint32_t k0 = (n - 1u) >> 1;
    float med[2], rs[2];
    uint32_t nab[2];
    #pragma unroll
    for (int w = 0; w < 2; w++) {
        float m = ((const float*)(ws + SH_OFF))[w * B + b];
        uint32_t k3 = ws[K_OFF + w * B + b];
        uint32_t e = ws[EQ_OFF + w * B + b];
        float SBv = ((const float*)(ws + SB_OFF))[w * B + b];
        float ST = ((const float*)(ws + TSUM_OFF))[w * B + b];
        uint32_t CB = k0 - k3;                    // count strictly below median
        uint32_t na = n - CB - e;                 // count strictly above
        float Sab = ST - SBv - (float)e * m;      // sum of values above median
        float absdev = (Sab - (float)na * m) + ((float)CB * m - SBv);
        float scale = absdev / (float)n;
        med[w] = m; nab[w] = na;
        rs[w] = 1.f / scale;
        ((float*)(ws + RS_OFF))[w * B + b] = rs[w];
    }
    uint32_t c2 = nab[1];                         // count(targ > st)
    ws[C2_OFF + b] = c2;
    uint32_t mi = (uint32_t)NPX - c2 + (uint32_t)TRIM_IDX;
    if (mi > (uint32_t)(NPX - 1)) mi = NPX - 1;
    float p = pred[(size_t)b * NPX + mi];
    float t = targ[(size_t)b * NPX + mi];
    float pn = (p - med[0]) * rs[0], tn = (t - med[1]) * rs[1];
    ((float*)(ws + THR_OFF))[b] = (tn > 0.f) ? fabsf(pn - tn) : 0.f;
}

// ---------------- fused loss: 8-row strip per wave, 2-deep register ring ----------------
__global__ void __launch_bounds__(256) loss_kernel(const float* __restrict__ pred,
                                                   const float* __restrict__ targ,
                                                   uint32_t* __restrict__ ws) {
    const int wid = (blockIdx.x << 2) + (threadIdx.x >> 6);   // strip id
    const int b = wid / (H / RPW);
    const int s0 = (wid - b * (H / RPW)) * RPW;               // first row (multiple of 8)
    const int l = threadIdx.x & 63;
    const int col = l << 3;
    const float sp = ((const float*)(ws + SH_OFF))[b];
    const float st = ((const float*)(ws + SH_OFF))[B + b];
    const float rp = ((const float*)(ws + RS_OFF))[b];
    const float rt = ((const float*)(ws + RS_OFF))[B + b];
    const float thr = ((const float*)(ws + THR_OFF))[b];
    const float* Pp = pred + (size_t)b * NPX;
    const float* Tp = targ + (size_t)b * NPX;

    const bool g1 = s0 >= 1, g2 = s0 >= 2, g4 = s0 >= 4, g8 = s0 >= 8;
    float rT[2][8], rPN[2][8];
    {
        const int roA = (g1 ? (s0 - 1) : s0) * W + col;
        const int roB = (g2 ? (s0 - 2) : s0) * W + col;
        float4 a0 = *(const float4*)(Tp + roA), a1 = *(const float4*)(Tp + roA + 4);
        float4 b0 = *(const float4*)(Pp + roA), b1 = *(const float4*)(Pp + roA + 4);
        float4 c0 = *(const float4*)(Tp + roB), c1 = *(const float4*)(Tp + roB + 4);
        float4 d0 = *(const float4*)(Pp + roB), d1 = *(const float4*)(Pp + roB + 4);
        float ta[8] = {a0.x,a0.y,a0.z,a0.w,a1.x,a1.y,a1.z,a1.w};
        float pa[8] = {b0.x,b0.y,b0.z,b0.w,b1.x,b1.y,b1.z,b1.w};
        float tc[8] = {c0.x,c0.y,c0.z,c0.w,c1.x,c1.y,c1.z,c1.w};
        float pc[8] = {d0.x,d0.y,d0.z,d0.w,d1.x,d1.y,d1.z,d1.w};
        #pragma unroll
        for (int k = 0; k < 8; k++) {
            rT[1][k] = ta[k]; rPN[1][k] = (pa[k] - sp) * rp;
            rT[0][k] = tc[k]; rPN[0][k] = (pc[k] - sp) * rp;
        }
    }

    float tl = 0.f, gl0 = 0.f, gl1 = 0.f, gl2 = 0.f, gl3 = 0.f;
    uint32_t mc = 0;

    #pragma unroll
    for (int it = 0; it < RPW; ++it) {
        const int ro = (s0 + it) * W + col;
        const int cur = it & 1, prv = cur ^ 1;
        float4 a0 = *(const float4*)(Tp + ro), a1 = *(const float4*)(Tp + ro + 4);
        float4 b0 = *(const float4*)(Pp + ro), b1 = *(const float4*)(Pp + ro + 4);
        float t[8] = {a0.x,a0.y,a0.z,a0.w,a1.x,a1.y,a1.z,a1.w};
        float p[8] = {b0.x,b0.y,b0.z,b0.w,b1.x,b1.y,b1.z,b1.w};
        float t4a = 0.f, t4b = 0.f, p4a = 0.f, p4b = 0.f, t8a = 0.f, p8a = 0.f;
        if (it == 0) {
            const int ro4 = g4 ? ro - 4 * W : ro;
            t4a = Tp[ro4]; t4b = Tp[ro4 + 4]; p4a = Pp[ro4]; p4b = Pp[ro4 + 4];
            const int ro8 = g8 ? ro - 8 * W : ro;
            t8a = Tp[ro8]; p8a = Pp[ro8];
        }
        if (it == 4) {
            const int ro4 = ro - 4 * W;
            t4a = Tp[ro4]; t4b = Tp[ro4 + 4]; p4a = Pp[ro4]; p4b = Pp[ro4 + 4];
        }
        float pn[8]; bool m[8];
        #pragma unroll
        for (int k = 0; k < 8; k++) { pn[k] = (p[k] - sp) * rp; m[k] = t[k] > st; }

        #pragma unroll
        for (int k = 0; k < 8; k++) {
            if (m[k]) {
                float tn = (t[k] - st) * rt;
                float r = fabsf(pn[k] - tn);
                if (r <= thr) tl += r;
            }
        }
        float t7p = __shfl_up(t[7], 1), pn7p = __shfl_up(pn[7], 1);
        if (l > 0 && m[0] && t7p > st) gl0 += fabsf(pn[0] - pn7p);
        #pragma unroll
        for (int k = 1; k < 8; k++) if (m[k] && m[k - 1]) gl0 += fabsf(pn[k] - pn[k - 1]);
        if (it > 0 || g1) {
            #pragma unroll
            for (int k = 0; k < 8; k++)
                if (m[k] && rT[prv][k] > st) gl0 += fabsf(pn[k] - rPN[prv][k]);
        }
        if ((it & 1) == 0) {
            float t6p = __shfl_up(t[6], 1), pn6p = __shfl_up(pn[6], 1);
            mc += (uint32_t)m[0] + m[2] + m[4] + m[6];
            if (l > 0 && m[0] && t6p > st) gl1 += fabsf(pn[0] - pn6p);
            if (m[2] && m[0]) gl1 += fabsf(pn[2] - pn[0]);
            if (m[4] && m[2]) gl1 += fabsf(pn[4] - pn[2]);
            if (m[6] && m[4]) gl1 += fabsf(pn[6] - pn[4]);
            if (it >= 2 || g2) {
                if (m[0] && rT[cur][0] > st) gl1 += fabsf(pn[0] - rPN[cur][0]);
                if (m[2] && rT[cur][2] > st) gl1 += fabsf(pn[2] - rPN[cur][2]);
                if (m[4] && rT[cur][4] > st) gl1 += fabsf(pn[4] - rPN[cur][4]);
                if (m[6] && rT[cur][6] > st) gl1 += fabsf(pn[6] - rPN[cur][6]);
            }
            if ((it & 3) == 0) {
                float t4p = __shfl_up(t[4], 1), pn4p = __shfl_up(pn[4], 1);
                mc += ((uint32_t)m[0] + m[4]) << 11;
                if (l > 0 && m[0] && t4p > st) gl2 += fabsf(pn[0] - pn4p);
                if (m[4] && m[0]) gl2 += fabsf(pn[4] - pn[0]);
                if (it == 4 || g4) {
                    if (m[0] && t4a > st) gl2 += fabsf(pn[0] - (p4a - sp) * rp);
                    if (m[4] && t4b > st) gl2 += fabsf(pn[4] - (p4b - sp) * rp);
                }
                if (it == 0) {
                    float t0p = __shfl_up(t[0], 1), pn0p = __shfl_up(pn[0], 1);
                    mc += ((uint32_t)m[0]) << 22;
                    if (l > 0 && m[0] && t0p > st) gl3 += fabsf(pn[0] - pn0p);
                    if (g8 && m[0] && t8a > st) gl3 += fabsf(pn[0] - (p8a - sp) * rp);
                }
            }
        }
        #pragma unroll
        for (int k = 0; k < 8; k++) { rT[cur][k] = t[k]; rPN[cur][k] = pn[k]; }
    }

    for (int off = 32; off; off >>= 1) {
        tl  += __shfl_down(tl, off, 64);
        gl0 += __shfl_down(gl0, off, 64);
        gl1 += __shfl_down(gl1, off, 64);
        gl2 += __shfl_down(gl2, off, 64);
        gl3 += __shfl_down(gl3, off, 64);
        mc  += __shfl_down(mc, off, 64);
    }
    if (l == 0) {
        float* gs = (float*)(ws + GS_OFF);
        atomicAdd(((float*)(ws + TS_OFF)) + b, tl);
        atomicAdd(gs + b, gl0);
        atomicAdd(gs + B + b, gl1);
        atomicAdd(gs + 2 * B + b, gl2);
        atomicAdd(gs + 3 * B + b, gl3);
        atomicAdd(ws + MS_OFF + b, mc & 0x7FFu);
        atomicAdd(ws + MS_OFF + B + b, (mc >> 11) & 0x7FFu);
        atomicAdd(ws + MS_OFF + 2 * B + b, mc >> 22);
    }
}

// ---------------- finalize ----------------
__global__ void finalize_kernel(const uint32_t* __restrict__ ws, float* __restrict__ out) {
    const int b = threadIdx.x;
    float v = 0.f;
    if (b < B) {
        float c2 = (float)ws[C2_OFF + b];
        const float* tsum = (const float*)(ws + TS_OFF);
        const float* gsum = (const float*)(ws + GS_OFF);
        float tm = (c2 > 0.f) ? tsum[b] / (2.f * c2) : 0.f;
        float g = (c2 > 0.f) ? gsum[b] / c2 : 0.f;
        for (int z = 0; z < 3; z++) {
            float ms = (float)ws[MS_OFF + z * B + b];
            g += (ms > 0.f) ? gsum[(1 + z) * B + b] / ms : 0.f;
        }
        v = tm + 0.5f * g;
    }
    for (int off = 32; off; off >>= 1) v += __shfl_down(v, off, 64);
    if (b == 0) out[0] = v * (1.f / 64.f);
}

extern "C" void kernel_launch(void* const* d_in, const int* in_sizes, int n_in,
                              void* d_out, int out_size, void* d_ws, size_t ws_size,
                              hipStream_t stream) {
    const float* pred = (const float*)d_in[0];
    const float* targ = (const float*)d_in[1];
    float* out = (float*)d_out;
    uint32_t* ws = (uint32_t*)d_ws;

    // choose candidate-buffer capacity from available workspace (deterministic)
    long avail = (long)(ws_size / 4) - (long)FIX_U32;
    int cap = 0;
    if (avail >= 128L * 2048) {
        long c = avail / 128;
        cap = (int)(c < CAPMAX ? c : CAPMAX);
    }

    hipMemsetAsync(ws, 0, (size_t)ZERO_U32 * 4, stream);

    hist1_kernel<<<dim3(32, B), 256, 0, stream>>>(pred, targ, ws);
    select1_kernel<<<dim3(B, 2), 256, 0, stream>>>(ws);
    collect2_kernel<<<dim3(64, B), 256, 0, stream>>>(pred, targ, ws, cap);
    small3_kernel<<<dim3(B, 2), 256, 0, stream>>>(pred, targ, ws, cap);
    param_kernel<<<1, 64, 0, stream>>>(pred, targ, ws);
    loss_kernel<<<dim3(B * (H / RPW) / 4), 256, 0, stream>>>(pred, targ, ws);
    finalize_kernel<<<1, 64, 0, stream>>>(ws, out);
}

// Round 9
// 190.832 us; speedup vs baseline: 1.5267x; 1.5267x over previous
//
#include <hip/hip_runtime.h>
#include <stdint.h>

#define B 64
#define H 384
#define W 512
#define NPX (H*W)            // 196608
#define TRIM_IDX 157286      // int(0.8 * 196608)
#define RPW 8                // rows per wave in loss kernel

#define NB1 4096             // stage1 bins (12 bits)
#define NBA 2048             // small3 pass A bins (11 bits)
#define NBB 512              // small3 pass B bins (9 bits)
#define CAPW 256             // per-wave candidate cap
#define NSLOT 64             // waves per sample in collect2

// ---- workspace layout (uint32 units) ----
#define HIST_U32 (2*B*NB1)               // 524288 u32 = 2 MB
#define ACC_OFF  HIST_U32
#define N_OFF    (ACC_OFF + 0)           // [B]  u32 mask count
#define MS_OFF   (ACC_OFF + 64)          // [3][B] u32 subsample mask counts
#define TS_OFF   (ACC_OFF + 256)         // [B]  f32 tmae sum
#define GS_OFF   (ACC_OFF + 320)         // [4][B] f32 grad sums
#define TSUM_OFF (ACC_OFF + 576)         // [2][B] f32 total masked value sum
#define SB_OFF   (ACC_OFF + 704)         // [2][B] f32 sum of masked values < med
#define OVF_OFF  (ACC_OFF + 832)         // [2][B] u32 per-wave-buffer overflow flag
#define ZERO_U32 (ACC_OFF + 960)
// persistent (written before read each launch)
#define K_OFF    (ACC_OFF + 960)         // [2][B] u32 rank (k1 then k3)
#define PFX_OFF  (ACC_OFF + 1088)        // [2][B] u32 stage-1 bin (12 bits)
#define EQ_OFF   (ACC_OFF + 1216)        // [2][B] u32 count equal to median
#define SH_OFF   (ACC_OFF + 1344)        // [2][B] f32 median (shift)
#define RS_OFF   (ACC_OFF + 1472)        // [2][B] f32 reciprocal scale
#define THR_OFF  (ACC_OFF + 1600)        // [B]  f32 trim threshold
#define C2_OFF   (ACC_OFF + 1664)        // [B]  u32 count targ>shift_t
#define CNT1_OFF (ACC_OFF + 1728)        // [2][B] u32 stage-1 bin size
#define CNTW_OFF (ACC_OFF + 1856)        // [2][B][NSLOT] u32 per-wave counts
#define FIX_U32  (ACC_OFF + 1856 + 2*B*NSLOT)
#define BUF_OFF  FIX_U32                 // [2][B][NSLOT][capw] f32 candidates

__device__ __forceinline__ uint32_t fmap(float f) {
    uint32_t b = __float_as_uint(f);
    return (b & 0x80000000u) ? ~b : (b | 0x80000000u);
}
__device__ __forceinline__ float funmap(uint32_t u) {
    uint32_t b = (u & 0x80000000u) ? (u & 0x7fffffffu) : ~u;
    return __uint_as_float(b);
}

// ---------------- stage 1: 12-bit histogram + n + total sums ----------------
// grid (16,B) x 256: 48 elems/thread/array, 3 rounds of 8 hoisted float4 loads
__global__ void __launch_bounds__(256) hist1_kernel(const float* __restrict__ pred,
                                                    const float* __restrict__ targ,
                                                    uint32_t* __restrict__ ws) {
    __shared__ uint32_t lh[2 * NB1];     // 32 KB
    const int b = blockIdx.y;
    for (int i = threadIdx.x; i < 2 * NB1; i += 256) lh[i] = 0;
    __syncthreads();
    const float4* pb = (const float4*)(pred + (size_t)b * NPX);
    const float4* tb = (const float4*)(targ + (size_t)b * NPX);
    const int tid = blockIdx.x * 256 + threadIdx.x;   // [0,4096)
    uint32_t nloc = 0;
    float sump = 0.f, sumt = 0.f;
    #pragma unroll
    for (int r = 0; r < 3; r++) {
        float4 ta0 = tb[tid + (4*r+0)*4096], ta1 = tb[tid + (4*r+1)*4096];
        float4 ta2 = tb[tid + (4*r+2)*4096], ta3 = tb[tid + (4*r+3)*4096];
        float4 pa0 = pb[tid + (4*r+0)*4096], pa1 = pb[tid + (4*r+1)*4096];
        float4 pa2 = pb[tid + (4*r+2)*4096], pa3 = pb[tid + (4*r+3)*4096];
        float tA[16] = {ta0.x,ta0.y,ta0.z,ta0.w, ta1.x,ta1.y,ta1.z,ta1.w,
                        ta2.x,ta2.y,ta2.z,ta2.w, ta3.x,ta3.y,ta3.z,ta3.w};
        float pA[16] = {pa0.x,pa0.y,pa0.z,pa0.w, pa1.x,pa1.y,pa1.z,pa1.w,
                        pa2.x,pa2.y,pa2.z,pa2.w, pa3.x,pa3.y,pa3.z,pa3.w};
        #pragma unroll
        for (int e = 0; e < 16; e++) {
            float t = tA[e];
            if (t > 0.f) {
                float p = pA[e];
                nloc++; sumt += t; sump += p;
                atomicAdd(&lh[fmap(p) >> 20], 1u);
                atomicAdd(&lh[NB1 + (fmap(t) >> 20)], 1u);
            }
        }
    }
    __syncthreads();
    uint32_t* hist = ws;
    for (int i = threadIdx.x; i < 2 * NB1; i += 256) {
        uint32_t v = lh[i];
        if (v) {
            int which = i >> 12, bin = i & (NB1 - 1);
            atomicAdd(&hist[(size_t)(which * B + b) * NB1 + bin], v);
        }
    }
    for (int off = 32; off; off >>= 1) {
        nloc += __shfl_down(nloc, off, 64);
        sump += __shfl_down(sump, off, 64);
        sumt += __shfl_down(sumt, off, 64);
    }
    if ((threadIdx.x & 63) == 0) {
        if (nloc) atomicAdd(ws + N_OFF + b, nloc);
        atomicAdd(((float*)(ws + TSUM_OFF)) + b, sump);
        atomicAdd(((float*)(ws + TSUM_OFF)) + B + b, sumt);
    }
}

// ---------------- select stage 1 (4096 bins) ----------------
__global__ void select1_kernel(uint32_t* __restrict__ ws) {
    const int b = blockIdx.x, which = blockIdx.y;
    const uint32_t* h = ws + (size_t)(which * B + b) * NB1;
    const uint32_t k = (ws[N_OFF + b] - 1u) >> 1;
    const int t = threadIdx.x;
    uint32_t mysum = 0;
    #pragma unroll
    for (int i = 0; i < 16; i++) mysum += h[t * 16 + i];
    __shared__ uint32_t s[256];
    s[t] = mysum;
    __syncthreads();
    for (int off = 1; off < 256; off <<= 1) {
        uint32_t add = (t >= off) ? s[t - off] : 0u;
        __syncthreads();
        s[t] += add;
        __syncthreads();
    }
    uint32_t incl = s[t], excl = incl - mysum;
    if (k >= excl && k < incl) {
        uint32_t c = excl, bin = 0, newk = 0, e = 0;
        for (int i = 0; i < 16; i++) {
            uint32_t hv = h[t * 16 + i];
            if (k < c + hv) { bin = t * 16 + i; newk = k - c; e = hv; break; }
            c += hv;
        }
        ws[PFX_OFF + which * B + b] = bin;
        ws[K_OFF + which * B + b] = newk;
        ws[CNT1_OFF + which * B + b] = e;
    }
}

// ---------------- pass 2: barrier-less sum-below + wave-private compaction ----------------
// grid (16,B) x 256; each wave owns a private global slot; no LDS, no atomics for compaction
__global__ void __launch_bounds__(256) collect2_kernel(const float* __restrict__ pred,
                                                       const float* __restrict__ targ,
                                                       uint32_t* __restrict__ ws, int capw) {
    const int b = blockIdx.y;
    const int t = threadIdx.x;
    const int lane = t & 63;
    const int slot = (blockIdx.x << 2) + (t >> 6);    // [0,64)
    const uint32_t pfxp = ws[PFX_OFF + b];
    const uint32_t pfxt = ws[PFX_OFF + B + b];
    const float4* pb = (const float4*)(pred + (size_t)b * NPX);
    const float4* tb = (const float4*)(targ + (size_t)b * NPX);
    const int tid = blockIdx.x * 256 + t;
    float* bufp = ((float*)(ws + BUF_OFF)) + ((size_t)b * NSLOT + slot) * capw;
    float* buft = ((float*)(ws + BUF_OFF)) + (((size_t)B + b) * NSLOT + slot) * capw;
    float sbp = 0.f, sbt = 0.f;
    uint32_t wp = 0, wt = 0;                          // wave-uniform running counts
    #pragma unroll
    for (int r = 0; r < 3; r++) {
        float4 ta0 = tb[tid + (4*r+0)*4096], ta1 = tb[tid + (4*r+1)*4096];
        float4 ta2 = tb[tid + (4*r+2)*4096], ta3 = tb[tid + (4*r+3)*4096];
        float4 pa0 = pb[tid + (4*r+0)*4096], pa1 = pb[tid + (4*r+1)*4096];
        float4 pa2 = pb[tid + (4*r+2)*4096], pa3 = pb[tid + (4*r+3)*4096];
        float tA[16] = {ta0.x,ta0.y,ta0.z,ta0.w, ta1.x,ta1.y,ta1.z,ta1.w,
                        ta2.x,ta2.y,ta2.z,ta2.w, ta3.x,ta3.y,ta3.z,ta3.w};
        float pA[16] = {pa0.x,pa0.y,pa0.z,pa0.w, pa1.x,pa1.y,pa1.z,pa1.w,
                        pa2.x,pa2.y,pa2.z,pa2.w, pa3.x,pa3.y,pa3.z,pa3.w};
        uint32_t mbp = 0, mbt = 0;                    // match bitmasks
        #pragma unroll
        for (int e = 0; e < 16; e++) {
            float tv = tA[e], pv = pA[e];
            bool msk = tv > 0.f;
            uint32_t u1p = fmap(pv) >> 20, u1t = fmap(tv) >> 20;
            if (msk && u1p < pfxp) sbp += pv;
            if (msk && u1t < pfxt) sbt += tv;
            if (msk && u1p == pfxp) mbp |= (1u << e);
            if (msk && u1t == pfxt) mbt |= (1u << e);
        }
        uint32_t packed = (uint32_t)__popc(mbp) | ((uint32_t)__popc(mbt) << 16);
        uint32_t scan = packed;
        #pragma unroll
        for (int off = 1; off < 64; off <<= 1) {
            uint32_t v = (uint32_t)__shfl_up((int)scan, off, 64);
            if (lane >= off) scan += v;
        }
        uint32_t tot = (uint32_t)__shfl((int)scan, 63, 64);
        uint32_t exl = scan - packed;
        uint32_t op = wp + (exl & 0xFFFFu);
        uint32_t ot = wt + (exl >> 16);
        if (mbp | mbt) {
            #pragma unroll
            for (int e = 0; e < 16; e++) {
                if ((mbp >> e) & 1u) { if (op < (uint32_t)capw) bufp[op] = pA[e]; op++; }
                if ((mbt >> e) & 1u) { if (ot < (uint32_t)capw) buft[ot] = tA[e]; ot++; }
            }
        }
        wp += tot & 0xFFFFu;
        wt += tot >> 16;
    }
    if (lane == 0) {
        ws[CNTW_OFF + b * NSLOT + slot] = wp;
        ws[CNTW_OFF + (B + b) * NSLOT + slot] = wt;
        if (wp > (uint32_t)capw) ws[OVF_OFF + b] = 1u;
        if (wt > (uint32_t)capw) ws[OVF_OFF + B + b] = 1u;
    }
    for (int off = 32; off; off >>= 1) {
        sbp += __shfl_down(sbp, off, 64);
        sbt += __shfl_down(sbt, off, 64);
    }
    if (lane == 0) {
        atomicAdd(((float*)(ws + SB_OFF)) + b, sbp);
        atomicAdd(((float*)(ws + SB_OFF)) + B + b, sbt);
    }
}

// ---------------- small select: finish remaining 20 bits (11 + 9) ----------------
__global__ void small3_kernel(const float* __restrict__ pred,
                              const float* __restrict__ targ,
                              uint32_t* __restrict__ ws, int capw) {
    const int b = blockIdx.x, which = blockIdx.y;
    const int t = threadIdx.x;
    __shared__ uint32_t cnt[NBA];
    __shared__ float fsm[NBA];
    __shared__ uint32_t sc[256];
    __shared__ float sfl[256];
    __shared__ uint32_t r_bin, r_k;
    __shared__ float r_f;
    const uint32_t pfx1 = ws[PFX_OFF + which * B + b];
    const uint32_t k1 = ws[K_OFF + which * B + b];
    const bool fast = (capw > 0) && (ws[OVF_OFF + which * B + b] == 0u);
    const uint32_t* cw = ws + CNTW_OFF + (which * B + b) * NSLOT;
    const float* bufb = ((const float*)(ws + BUF_OFF)) + ((size_t)which * B + b) * NSLOT * capw;
    const float* Tp = targ + (size_t)b * NPX;
    const float* Pp = pred + (size_t)b * NPX;

    // ---- pass A: mid 11 bits ----
    for (int i = t; i < NBA; i += 256) { cnt[i] = 0; fsm[i] = 0.f; }
    __syncthreads();
    if (fast) {
        for (int s = 0; s < NSLOT; s++) {
            uint32_t n = cw[s];
            const float* sb_ = bufb + (size_t)s * capw;
            for (uint32_t j = t; j < n; j += 256) {
                float v = sb_[j];
                uint32_t u = fmap(v), mb = (u >> 9) & (NBA - 1u);
                atomicAdd(&cnt[mb], 1u); atomicAdd(&fsm[mb], v);
            }
        }
    } else {
        for (int j = t; j < NPX; j += 256) {
            float tvv = Tp[j];
            if (tvv > 0.f) {
                float v = (which == 0) ? Pp[j] : tvv;
                uint32_t u = fmap(v);
                if ((u >> 20) == pfx1) {
                    uint32_t mb = (u >> 9) & (NBA - 1u);
                    atomicAdd(&cnt[mb], 1u); atomicAdd(&fsm[mb], v);
                }
            }
        }
    }
    __syncthreads();
    {
        uint32_t ms = 0; float mf = 0.f;
        #pragma unroll
        for (int i = 0; i < 8; i++) { ms += cnt[t * 8 + i]; mf += fsm[t * 8 + i]; }
        sc[t] = ms; sfl[t] = mf;
        __syncthreads();
        for (int off = 1; off < 256; off <<= 1) {
            uint32_t a = (t >= off) ? sc[t - off] : 0u;
            float af = (t >= off) ? sfl[t - off] : 0.f;
            __syncthreads();
            sc[t] += a; sfl[t] += af;
            __syncthreads();
        }
        uint32_t incl = sc[t], excl = incl - ms;
        float fx = sfl[t] - mf;
        if (k1 >= excl && k1 < incl) {
            uint32_t c = excl, bin = 0, nk = 0; float f = fx;
            for (int i = 0; i < 8; i++) {
                uint32_t hv = cnt[t * 8 + i];
                if (k1 < c + hv) { bin = t * 8 + i; nk = k1 - c; break; }
                c += hv; f += fsm[t * 8 + i];
            }
            r_bin = bin; r_k = nk; r_f = f;
        }
    }
    __syncthreads();
    const uint32_t mid_sel = r_bin, k2 = r_k;
    const float fbelowA = r_f;
    __syncthreads();
    // ---- pass B: low 9 bits ----
    for (int i = t; i < NBB; i += 256) { cnt[i] = 0; fsm[i] = 0.f; }
    __syncthreads();
    if (fast) {
        for (int s = 0; s < NSLOT; s++) {
            uint32_t n = cw[s];
            const float* sb_ = bufb + (size_t)s * capw;
            for (uint32_t j = t; j < n; j += 256) {
                float v = sb_[j];
                uint32_t u = fmap(v);
                if (((u >> 9) & (NBA - 1u)) == mid_sel) {
                    uint32_t lb = u & (NBB - 1u);
                    atomicAdd(&cnt[lb], 1u); atomicAdd(&fsm[lb], v);
                }
            }
        }
    } else {
        for (int j = t; j < NPX; j += 256) {
            float tvv = Tp[j];
            if (tvv > 0.f) {
                float v = (which == 0) ? Pp[j] : tvv;
                uint32_t u = fmap(v);
                if ((u >> 20) == pfx1 && ((u >> 9) & (NBA - 1u)) == mid_sel) {
                    uint32_t lb = u & (NBB - 1u);
                    atomicAdd(&cnt[lb], 1u); atomicAdd(&fsm[lb], v);
                }
            }
        }
    }
    __syncthreads();
    {
        uint32_t ms = 0; float mf = 0.f;
        #pragma unroll
        for (int i = 0; i < 2; i++) { ms += cnt[t * 2 + i]; mf += fsm[t * 2 + i]; }
        sc[t] = ms; sfl[t] = mf;
        __syncthreads();
        for (int off = 1; off < 256; off <<= 1) {
            uint32_t a = (t >= off) ? sc[t - off] : 0u;
            float af = (t >= off) ? sfl[t - off] : 0.f;
            __syncthreads();
            sc[t] += a; sfl[t] += af;
            __syncthreads();
        }
        uint32_t incl = sc[t], excl = incl - ms;
        float fx = sfl[t] - mf;
        if (k2 >= excl && k2 < incl) {
            uint32_t c = excl, bin = 0, nk = 0, e = 0; float f = fx;
            for (int i = 0; i < 2; i++) {
                uint32_t hv = cnt[t * 2 + i];
                if (k2 < c + hv) { bin = t * 2 + i; nk = k2 - c; e = hv; break; }
                c += hv; f += fsm[t * 2 + i];
            }
            uint32_t u = (pfx1 << 20) | (mid_sel << 9) | bin;
            ((float*)(ws + SH_OFF))[which * B + b] = funmap(u);
            ws[K_OFF + which * B + b] = nk;      // k3
            ws[EQ_OFF + which * B + b] = e;
            ((float*)(ws + SB_OFF))[which * B + b] += fbelowA + f;
        }
    }
}

// ---------------- params ----------------
__global__ void param_kernel(const float* __restrict__ pred,
                             const float* __restrict__ targ,
                             uint32_t* __restrict__ ws) {
    const int b = threadIdx.x;
    if (b >= B) return;
    const uint32_t n = ws[N_OFF + b];
    const uint32_t k0 = (n - 1u) >> 1;
    float med[2], rs[2];
    uint32_t nab[2];
    #pragma unroll
    for (int w = 0; w < 2; w++) {
        float m = ((const float*)(ws + SH_OFF))[w * B + b];
        uint32_t k3 = ws[K_OFF + w * B + b];
        uint32_t e = ws[EQ_OFF + w * B + b];
        float SBv = ((const float*)(ws + SB_OFF))[w * B + b];
        float ST = ((const float*)(ws + TSUM_OFF))[w * B + b];
        uint32_t CB = k0 - k3;
        uint32_t na = n - CB - e;
        float Sab = ST - SBv - (float)e * m;
        float absdev = (Sab - (float)na * m) + ((float)CB * m - SBv);
        float scale = absdev / (float)n;
        med[w] = m; nab[w] = na;
        rs[w] = 1.f / scale;
        ((float*)(ws + RS_OFF))[w * B + b] = rs[w];
    }
    uint32_t c2 = nab[1];
    ws[C2_OFF + b] = c2;
    uint32_t mi = (uint32_t)NPX - c2 + (uint32_t)TRIM_IDX;
    if (mi > (uint32_t)(NPX - 1)) mi = NPX - 1;
    float p = pred[(size_t)b * NPX + mi];
    float t = targ[(size_t)b * NPX + mi];
    float pn = (p - med[0]) * rs[0], tn = (t - med[1]) * rs[1];
    ((float*)(ws + THR_OFF))[b] = (tn > 0.f) ? fabsf(pn - tn) : 0.f;
}

// ---------------- fused loss: 8-row strip per wave, 2-deep register ring ----------------
__global__ void __launch_bounds__(256) loss_kernel(const float* __restrict__ pred,
                                                   const float* __restrict__ targ,
                                                   uint32_t* __restrict__ ws) {
    const int wid = (blockIdx.x << 2) + (threadIdx.x >> 6);
    const int b = wid / (H / RPW);
    const int s0 = (wid - b * (H / RPW)) * RPW;
    const int l = threadIdx.x & 63;
    const int col = l << 3;
    const float sp = ((const float*)(ws + SH_OFF))[b];
    const float st = ((const float*)(ws + SH_OFF))[B + b];
    const float rp = ((const float*)(ws + RS_OFF))[b];
    const float rt = ((const float*)(ws + RS_OFF))[B + b];
    const float thr = ((const float*)(ws + THR_OFF))[b];
    const float* Pp = pred + (size_t)b * NPX;
    const float* Tp = targ + (size_t)b * NPX;

    const bool g1 = s0 >= 1, g2 = s0 >= 2, g4 = s0 >= 4, g8 = s0 >= 8;
    float rT[2][8], rPN[2][8];
    {
        const int roA = (g1 ? (s0 - 1) : s0) * W + col;
        const int roB = (g2 ? (s0 - 2) : s0) * W + col;
        float4 a0 = *(const float4*)(Tp + roA), a1 = *(const float4*)(Tp + roA + 4);
        float4 b0 = *(const float4*)(Pp + roA), b1 = *(const float4*)(Pp + roA + 4);
        float4 c0 = *(const float4*)(Tp + roB), c1 = *(const float4*)(Tp + roB + 4);
        float4 d0 = *(const float4*)(Pp + roB), d1 = *(const float4*)(Pp + roB + 4);
        float ta[8] = {a0.x,a0.y,a0.z,a0.w,a1.x,a1.y,a1.z,a1.w};
        float pa[8] = {b0.x,b0.y,b0.z,b0.w,b1.x,b1.y,b1.z,b1.w};
        float tc[8] = {c0.x,c0.y,c0.z,c0.w,c1.x,c1.y,c1.z,c1.w};
        float pc[8] = {d0.x,d0.y,d0.z,d0.w,d1.x,d1.y,d1.z,d1.w};
        #pragma unroll
        for (int k = 0; k < 8; k++) {
            rT[1][k] = ta[k]; rPN[1][k] = (pa[k] - sp) * rp;
            rT[0][k] = tc[k]; rPN[0][k] = (pc[k] - sp) * rp;
        }
    }

    float tl = 0.f, gl0 = 0.f, gl1 = 0.f, gl2 = 0.f, gl3 = 0.f;
    uint32_t mc = 0;

    #pragma unroll
    for (int it = 0; it < RPW; ++it) {
        const int ro = (s0 + it) * W + col;
        const int cur = it & 1, prv = cur ^ 1;
        float4 a0 = *(const float4*)(Tp + ro), a1 = *(const float4*)(Tp + ro + 4);
        float4 b0 = *(const float4*)(Pp + ro), b1 = *(const float4*)(Pp + ro + 4);
        float t[8] = {a0.x,a0.y,a0.z,a0.w,a1.x,a1.y,a1.z,a1.w};
        float p[8] = {b0.x,b0.y,b0.z,b0.w,b1.x,b1.y,b1.z,b1.w};
        float t4a = 0.f, t4b = 0.f, p4a = 0.f, p4b = 0.f, t8a = 0.f, p8a = 0.f;
        if (it == 0) {
            const int ro4 = g4 ? ro - 4 * W : ro;
            t4a = Tp[ro4]; t4b = Tp[ro4 + 4]; p4a = Pp[ro4]; p4b = Pp[ro4 + 4];
            const int ro8 = g8 ? ro - 8 * W : ro;
            t8a = Tp[ro8]; p8a = Pp[ro8];
        }
        if (it == 4) {
            const int ro4 = ro - 4 * W;
            t4a = Tp[ro4]; t4b = Tp[ro4 + 4]; p4a = Pp[ro4]; p4b = Pp[ro4 + 4];
        }
        float pn[8]; bool m[8];
        #pragma unroll
        for (int k = 0; k < 8; k++) { pn[k] = (p[k] - sp) * rp; m[k] = t[k] > st; }

        #pragma unroll
        for (int k = 0; k < 8; k++) {
            if (m[k]) {
                float tn = (t[k] - st) * rt;
                float r = fabsf(pn[k] - tn);
                if (r <= thr) tl += r;
            }
        }
        float t7p = __shfl_up(t[7], 1), pn7p = __shfl_up(pn[7], 1);
        if (l > 0 && m[0] && t7p > st) gl0 += fabsf(pn[0] - pn7p);
        #pragma unroll
        for (int k = 1; k < 8; k++) if (m[k] && m[k - 1]) gl0 += fabsf(pn[k] - pn[k - 1]);
        if (it > 0 || g1) {
            #pragma unroll
            for (int k = 0; k < 8; k++)
                if (m[k] && rT[prv][k] > st) gl0 += fabsf(pn[k] - rPN[prv][k]);
        }
        if ((it & 1) == 0) {
            float t6p = __shfl_up(t[6], 1), pn6p = __shfl_up(pn[6], 1);
            mc += (uint32_t)m[0] + m[2] + m[4] + m[6];
            if (l > 0 && m[0] && t6p > st) gl1 += fabsf(pn[0] - pn6p);
            if (m[2] && m[0]) gl1 += fabsf(pn[2] - pn[0]);
            if (m[4] && m[2]) gl1 += fabsf(pn[4] - pn[2]);
            if (m[6] && m[4]) gl1 += fabsf(pn[6] - pn[4]);
            if (it >= 2 || g2) {
                if (m[0] && rT[cur][0] > st) gl1 += fabsf(pn[0] - rPN[cur][0]);
                if (m[2] && rT[cur][2] > st) gl1 += fabsf(pn[2] - rPN[cur][2]);
                if (m[4] && rT[cur][4] > st) gl1 += fabsf(pn[4] - rPN[cur][4]);
                if (m[6] && rT[cur][6] > st) gl1 += fabsf(pn[6] - rPN[cur][6]);
            }
            if ((it & 3) == 0) {
                float t4p = __shfl_up(t[4], 1), pn4p = __shfl_up(pn[4], 1);
                mc += ((uint32_t)m[0] + m[4]) << 11;
                if (l > 0 && m[0] && t4p > st) gl2 += fabsf(pn[0] - pn4p);
                if (m[4] && m[0]) gl2 += fabsf(pn[4] - pn[0]);
                if (it == 4 || g4) {
                    if (m[0] && t4a > st) gl2 += fabsf(pn[0] - (p4a - sp) * rp);
                    if (m[4] && t4b > st) gl2 += fabsf(pn[4] - (p4b - sp) * rp);
                }
                if (it == 0) {
                    float t0p = __shfl_up(t[0], 1), pn0p = __shfl_up(pn[0], 1);
                    mc += ((uint32_t)m[0]) << 22;
                    if (l > 0 && m[0] && t0p > st) gl3 += fabsf(pn[0] - pn0p);
                    if (g8 && m[0] && t8a > st) gl3 += fabsf(pn[0] - (p8a - sp) * rp);
                }
            }
        }
        #pragma unroll
        for (int k = 0; k < 8; k++) { rT[cur][k] = t[k]; rPN[cur][k] = pn[k]; }
    }

    for (int off = 32; off; off >>= 1) {
        tl  += __shfl_down(tl, off, 64);
        gl0 += __shfl_down(gl0, off, 64);
        gl1 += __shfl_down(gl1, off, 64);
        gl2 += __shfl_down(gl2, off, 64);
        gl3 += __shfl_down(gl3, off, 64);
        mc  += __shfl_down(mc, off, 64);
    }
    if (l == 0) {
        float* gs = (float*)(ws + GS_OFF);
        atomicAdd(((float*)(ws + TS_OFF)) + b, tl);
        atomicAdd(gs + b, gl0);
        atomicAdd(gs + B + b, gl1);
        atomicAdd(gs + 2 * B + b, gl2);
        atomicAdd(gs + 3 * B + b, gl3);
        atomicAdd(ws + MS_OFF + b, mc & 0x7FFu);
        atomicAdd(ws + MS_OFF + B + b, (mc >> 11) & 0x7FFu);
        atomicAdd(ws + MS_OFF + 2 * B + b, mc >> 22);
    }
}

// ---------------- finalize ----------------
__global__ void finalize_kernel(const uint32_t* __restrict__ ws, float* __restrict__ out) {
    const int b = threadIdx.x;
    float v = 0.f;
    if (b < B) {
        float c2 = (float)ws[C2_OFF + b];
        const float* tsum = (const float*)(ws + TS_OFF);
        const float* gsum = (const float*)(ws + GS_OFF);
        float tm = (c2 > 0.f) ? tsum[b] / (2.f * c2) : 0.f;
        float g = (c2 > 0.f) ? gsum[b] / c2 : 0.f;
        for (int z = 0; z < 3; z++) {
            float ms = (float)ws[MS_OFF + z * B + b];
            g += (ms > 0.f) ? gsum[(1 + z) * B + b] / ms : 0.f;
        }
        v = tm + 0.5f * g;
    }
    for (int off = 32; off; off >>= 1) v += __shfl_down(v, off, 64);
    if (b == 0) out[0] = v * (1.f / 64.f);
}

extern "C" void kernel_launch(void* const* d_in, const int* in_sizes, int n_in,
                              void* d_out, int out_size, void* d_ws, size_t ws_size,
                              hipStream_t stream) {
    const float* pred = (const float*)d_in[0];
    const float* targ = (const float*)d_in[1];
    float* out = (float*)d_out;
    uint32_t* ws = (uint32_t*)d_ws;

    long avail = (long)(ws_size / 4) - (long)FIX_U32;
    int capw = 0;
    if (avail > 0) {
        long c = avail / (2L * B * NSLOT);
        capw = (int)(c < CAPW ? c : CAPW);
    }

    hipMemsetAsync(ws, 0, (size_t)ZERO_U32 * 4, stream);

    hist1_kernel<<<dim3(16, B), 256, 0, stream>>>(pred, targ, ws);
    select1_kernel<<<dim3(B, 2), 256, 0, stream>>>(ws);
    collect2_kernel<<<dim3(16, B), 256, 0, stream>>>(pred, targ, ws, capw);
    small3_kernel<<<dim3(B, 2), 256, 0, stream>>>(pred, targ, ws, capw);
    param_kernel<<<1, 64, 0, stream>>>(pred, targ, ws);
    loss_kernel<<<dim3(B * (H / RPW) / 4), 256, 0, stream>>>(pred, targ, ws);
    finalize_kernel<<<1, 64, 0, stream>>>(ws, out);
}

// Round 10
// 187.754 us; speedup vs baseline: 1.5518x; 1.0164x over previous
//
#include <hip/hip_runtime.h>
#include <stdint.h>

#define B 64
#define H 384
#define W 512
#define NPX (H*W)            // 196608
#define TRIM_IDX 157286      // int(0.8 * 196608)
#define RPW 8                // rows per wave in loss kernel

#define NB1 4096             // stage1 bins (12 bits)
#define NBA 2048             // small3 pass A bins (11 bits)
#define NBB 512              // small3 pass B bins (9 bits)
#define CAPW 256             // per-wave candidate cap
#define NSLOT 64             // waves per sample in collect2

// ---- workspace layout (uint32 units) ----
#define HIST_U32 (2*B*NB1)               // 524288 u32 = 2 MB
#define ACC_OFF  HIST_U32
#define N_OFF    (ACC_OFF + 0)           // [B]  u32 mask count
#define MS_OFF   (ACC_OFF + 64)          // [3][B] u32 subsample mask counts
#define TS_OFF   (ACC_OFF + 256)         // [B]  f32 tmae sum
#define GS_OFF   (ACC_OFF + 320)         // [4][B] f32 grad sums
#define TSUM_OFF (ACC_OFF + 576)         // [2][B] f32 total masked value sum
#define SB_OFF   (ACC_OFF + 704)         // [2][B] f32 sum of masked values < med
#define OVF_OFF  (ACC_OFF + 832)         // [2][B] u32 per-wave-buffer overflow flag
#define ZERO_U32 (ACC_OFF + 960)
// persistent (written before read each launch)
#define K_OFF    (ACC_OFF + 960)         // [2][B] u32 rank (k1 then k3)
#define PFX_OFF  (ACC_OFF + 1088)        // [2][B] u32 stage-1 bin (12 bits)
#define EQ_OFF   (ACC_OFF + 1216)        // [2][B] u32 count equal to median
#define SH_OFF   (ACC_OFF + 1344)        // [2][B] f32 median (shift)
#define RS_OFF   (ACC_OFF + 1472)        // [2][B] f32 reciprocal scale
#define THR_OFF  (ACC_OFF + 1600)        // [B]  f32 trim threshold
#define C2_OFF   (ACC_OFF + 1664)        // [B]  u32 count targ>shift_t
#define CNT1_OFF (ACC_OFF + 1728)        // [2][B] u32 stage-1 bin size
#define CNTW_OFF (ACC_OFF + 1856)        // [2][B][NSLOT] u32 per-wave counts
#define FIX_U32  (ACC_OFF + 1856 + 2*B*NSLOT)
#define BUF_OFF  FIX_U32                 // [2][B][NSLOT][capw] f32 candidates

__device__ __forceinline__ uint32_t fmap(float f) {
    uint32_t b = __float_as_uint(f);
    return (b & 0x80000000u) ? ~b : (b | 0x80000000u);
}
__device__ __forceinline__ float funmap(uint32_t u) {
    uint32_t b = (u & 0x80000000u) ? (u & 0x7fffffffu) : ~u;
    return __uint_as_float(b);
}

// ---------------- stage 1: 12-bit histogram + n + total sums ----------------
// grid (16,B) x 256: 48 elems/thread/array, 3 rounds of 8 hoisted float4 loads
__global__ void __launch_bounds__(256) hist1_kernel(const float* __restrict__ pred,
                                                    const float* __restrict__ targ,
                                                    uint32_t* __restrict__ ws) {
    __shared__ uint32_t lh[2 * NB1];     // 32 KB
    const int b = blockIdx.y;
    for (int i = threadIdx.x; i < 2 * NB1; i += 256) lh[i] = 0;
    __syncthreads();
    const float4* pb = (const float4*)(pred + (size_t)b * NPX);
    const float4* tb = (const float4*)(targ + (size_t)b * NPX);
    const int tid = blockIdx.x * 256 + threadIdx.x;   // [0,4096)
    uint32_t nloc = 0;
    float sump = 0.f, sumt = 0.f;
    #pragma unroll
    for (int r = 0; r < 3; r++) {
        float4 ta0 = tb[tid + (4*r+0)*4096], ta1 = tb[tid + (4*r+1)*4096];
        float4 ta2 = tb[tid + (4*r+2)*4096], ta3 = tb[tid + (4*r+3)*4096];
        float4 pa0 = pb[tid + (4*r+0)*4096], pa1 = pb[tid + (4*r+1)*4096];
        float4 pa2 = pb[tid + (4*r+2)*4096], pa3 = pb[tid + (4*r+3)*4096];
        float tA[16] = {ta0.x,ta0.y,ta0.z,ta0.w, ta1.x,ta1.y,ta1.z,ta1.w,
                        ta2.x,ta2.y,ta2.z,ta2.w, ta3.x,ta3.y,ta3.z,ta3.w};
        float pA[16] = {pa0.x,pa0.y,pa0.z,pa0.w, pa1.x,pa1.y,pa1.z,pa1.w,
                        pa2.x,pa2.y,pa2.z,pa2.w, pa3.x,pa3.y,pa3.z,pa3.w};
        #pragma unroll
        for (int e = 0; e < 16; e++) {
            float t = tA[e];
            if (t > 0.f) {
                float p = pA[e];
                nloc++; sumt += t; sump += p;
                atomicAdd(&lh[fmap(p) >> 20], 1u);
                atomicAdd(&lh[NB1 + (fmap(t) >> 20)], 1u);
            }
        }
    }
    __syncthreads();
    uint32_t* hist = ws;
    for (int i = threadIdx.x; i < 2 * NB1; i += 256) {
        uint32_t v = lh[i];
        if (v) {
            int which = i >> 12, bin = i & (NB1 - 1);
            atomicAdd(&hist[(size_t)(which * B + b) * NB1 + bin], v);
        }
    }
    for (int off = 32; off; off >>= 1) {
        nloc += __shfl_down(nloc, off, 64);
        sump += __shfl_down(sump, off, 64);
        sumt += __shfl_down(sumt, off, 64);
    }
    if ((threadIdx.x & 63) == 0) {
        if (nloc) atomicAdd(ws + N_OFF + b, nloc);
        atomicAdd(((float*)(ws + TSUM_OFF)) + b, sump);
        atomicAdd(((float*)(ws + TSUM_OFF)) + B + b, sumt);
    }
}

// ---------------- select stage 1 (4096 bins) ----------------
__global__ void select1_kernel(uint32_t* __restrict__ ws) {
    const int b = blockIdx.x, which = blockIdx.y;
    const uint32_t* h = ws + (size_t)(which * B + b) * NB1;
    const uint32_t k = (ws[N_OFF + b] - 1u) >> 1;
    const int t = threadIdx.x;
    uint32_t mysum = 0;
    #pragma unroll
    for (int i = 0; i < 16; i++) mysum += h[t * 16 + i];
    __shared__ uint32_t s[256];
    s[t] = mysum;
    __syncthreads();
    for (int off = 1; off < 256; off <<= 1) {
        uint32_t add = (t >= off) ? s[t - off] : 0u;
        __syncthreads();
        s[t] += add;
        __syncthreads();
    }
    uint32_t incl = s[t], excl = incl - mysum;
    if (k >= excl && k < incl) {
        uint32_t c = excl, bin = 0, newk = 0, e = 0;
        for (int i = 0; i < 16; i++) {
            uint32_t hv = h[t * 16 + i];
            if (k < c + hv) { bin = t * 16 + i; newk = k - c; e = hv; break; }
            c += hv;
        }
        ws[PFX_OFF + which * B + b] = bin;
        ws[K_OFF + which * B + b] = newk;
        ws[CNT1_OFF + which * B + b] = e;
    }
}

// ---------------- pass 2: barrier-less sum-below + wave-private compaction ----------------
// grid (16,B) x 256; each wave owns a private global slot; no LDS, no atomics for compaction
__global__ void __launch_bounds__(256) collect2_kernel(const float* __restrict__ pred,
                                                       const float* __restrict__ targ,
                                                       uint32_t* __restrict__ ws, int capw) {
    const int b = blockIdx.y;
    const int t = threadIdx.x;
    const int lane = t & 63;
    const int slot = (blockIdx.x << 2) + (t >> 6);    // [0,64)
    const uint32_t pfxp = ws[PFX_OFF + b];
    const uint32_t pfxt = ws[PFX_OFF + B + b];
    const float4* pb = (const float4*)(pred + (size_t)b * NPX);
    const float4* tb = (const float4*)(targ + (size_t)b * NPX);
    const int tid = blockIdx.x * 256 + t;
    float* bufp = ((float*)(ws + BUF_OFF)) + ((size_t)b * NSLOT + slot) * capw;
    float* buft = ((float*)(ws + BUF_OFF)) + (((size_t)B + b) * NSLOT + slot) * capw;
    float sbp = 0.f, sbt = 0.f;
    uint32_t wp = 0, wt = 0;                          // wave-uniform running counts
    #pragma unroll
    for (int r = 0; r < 3; r++) {
        float4 ta0 = tb[tid + (4*r+0)*4096], ta1 = tb[tid + (4*r+1)*4096];
        float4 ta2 = tb[tid + (4*r+2)*4096], ta3 = tb[tid + (4*r+3)*4096];
        float4 pa0 = pb[tid + (4*r+0)*4096], pa1 = pb[tid + (4*r+1)*4096];
        float4 pa2 = pb[tid + (4*r+2)*4096], pa3 = pb[tid + (4*r+3)*4096];
        float tA[16] = {ta0.x,ta0.y,ta0.z,ta0.w, ta1.x,ta1.y,ta1.z,ta1.w,
                        ta2.x,ta2.y,ta2.z,ta2.w, ta3.x,ta3.y,ta3.z,ta3.w};
        float pA[16] = {pa0.x,pa0.y,pa0.z,pa0.w, pa1.x,pa1.y,pa1.z,pa1.w,
                        pa2.x,pa2.y,pa2.z,pa2.w, pa3.x,pa3.y,pa3.z,pa3.w};
        uint32_t mbp = 0, mbt = 0;                    // match bitmasks
        #pragma unroll
        for (int e = 0; e < 16; e++) {
            float tv = tA[e], pv = pA[e];
            bool msk = tv > 0.f;
            uint32_t u1p = fmap(pv) >> 20, u1t = fmap(tv) >> 20;
            if (msk && u1p < pfxp) sbp += pv;
            if (msk && u1t < pfxt) sbt += tv;
            if (msk && u1p == pfxp) mbp |= (1u << e);
            if (msk && u1t == pfxt) mbt |= (1u << e);
        }
        uint32_t packed = (uint32_t)__popc(mbp) | ((uint32_t)__popc(mbt) << 16);
        uint32_t scan = packed;
        #pragma unroll
        for (int off = 1; off < 64; off <<= 1) {
            uint32_t v = (uint32_t)__shfl_up((int)scan, off, 64);
            if (lane >= off) scan += v;
        }
        uint32_t tot = (uint32_t)__shfl((int)scan, 63, 64);
        uint32_t exl = scan - packed;
        uint32_t op = wp + (exl & 0xFFFFu);
        uint32_t ot = wt + (exl >> 16);
        if (mbp | mbt) {
            #pragma unroll
            for (int e = 0; e < 16; e++) {
                if ((mbp >> e) & 1u) { if (op < (uint32_t)capw) bufp[op] = pA[e]; op++; }
                if ((mbt >> e) & 1u) { if (ot < (uint32_t)capw) buft[ot] = tA[e]; ot++; }
            }
        }
        wp += tot & 0xFFFFu;
        wt += tot >> 16;
    }
    if (lane == 0) {
        ws[CNTW_OFF + b * NSLOT + slot] = wp;
        ws[CNTW_OFF + (B + b) * NSLOT + slot] = wt;
        if (wp > (uint32_t)capw) ws[OVF_OFF + b] = 1u;
        if (wt > (uint32_t)capw) ws[OVF_OFF + B + b] = 1u;
    }
    for (int off = 32; off; off >>= 1) {
        sbp += __shfl_down(sbp, off, 64);
        sbt += __shfl_down(sbt, off, 64);
    }
    if (lane == 0) {
        atomicAdd(((float*)(ws + SB_OFF)) + b, sbp);
        atomicAdd(((float*)(ws + SB_OFF)) + B + b, sbt);
    }
}

// ---------------- small select: finish remaining 20 bits (11 + 9) ----------------
__global__ void small3_kernel(const float* __restrict__ pred,
                              const float* __restrict__ targ,
                              uint32_t* __restrict__ ws, int capw) {
    const int b = blockIdx.x, which = blockIdx.y;
    const int t = threadIdx.x;
    __shared__ uint32_t cnt[NBA];
    __shared__ float fsm[NBA];
    __shared__ uint32_t sc[256];
    __shared__ float sfl[256];
    __shared__ uint32_t r_bin, r_k;
    __shared__ float r_f;
    const uint32_t pfx1 = ws[PFX_OFF + which * B + b];
    const uint32_t k1 = ws[K_OFF + which * B + b];
    const bool fast = (capw > 0) && (ws[OVF_OFF + which * B + b] == 0u);
    const uint32_t* cw = ws + CNTW_OFF + (which * B + b) * NSLOT;
    const float* bufb = ((const float*)(ws + BUF_OFF)) + ((size_t)which * B + b) * NSLOT * capw;
    const float* Tp = targ + (size_t)b * NPX;
    const float* Pp = pred + (size_t)b * NPX;

    // ---- pass A: mid 11 bits ----
    for (int i = t; i < NBA; i += 256) { cnt[i] = 0; fsm[i] = 0.f; }
    __syncthreads();
    if (fast) {
        for (int s = 0; s < NSLOT; s++) {
            uint32_t n = cw[s];
            const float* sb_ = bufb + (size_t)s * capw;
            for (uint32_t j = t; j < n; j += 256) {
                float v = sb_[j];
                uint32_t u = fmap(v), mb = (u >> 9) & (NBA - 1u);
                atomicAdd(&cnt[mb], 1u); atomicAdd(&fsm[mb], v);
            }
        }
    } else {
        for (int j = t; j < NPX; j += 256) {
            float tvv = Tp[j];
            if (tvv > 0.f) {
                float v = (which == 0) ? Pp[j] : tvv;
                uint32_t u = fmap(v);
                if ((u >> 20) == pfx1) {
                    uint32_t mb = (u >> 9) & (NBA - 1u);
                    atomicAdd(&cnt[mb], 1u); atomicAdd(&fsm[mb], v);
                }
            }
        }
    }
    __syncthreads();
    {
        uint32_t ms = 0; float mf = 0.f;
        #pragma unroll
        for (int i = 0; i < 8; i++) { ms += cnt[t * 8 + i]; mf += fsm[t * 8 + i]; }
        sc[t] = ms; sfl[t] = mf;
        __syncthreads();
        for (int off = 1; off < 256; off <<= 1) {
            uint32_t a = (t >= off) ? sc[t - off] : 0u;
            float af = (t >= off) ? sfl[t - off] : 0.f;
            __syncthreads();
            sc[t] += a; sfl[t] += af;
            __syncthreads();
        }
        uint32_t incl = sc[t], excl = incl - ms;
        float fx = sfl[t] - mf;
        if (k1 >= excl && k1 < incl) {
            uint32_t c = excl, bin = 0, nk = 0; float f = fx;
            for (int i = 0; i < 8; i++) {
                uint32_t hv = cnt[t * 8 + i];
                if (k1 < c + hv) { bin = t * 8 + i; nk = k1 - c; break; }
                c += hv; f += fsm[t * 8 + i];
            }
            r_bin = bin; r_k = nk; r_f = f;
        }
    }
    __syncthreads();
    const uint32_t mid_sel = r_bin, k2 = r_k;
    const float fbelowA = r_f;
    __syncthreads();
    // ---- pass B: low 9 bits ----
    for (int i = t; i < NBB; i += 256) { cnt[i] = 0; fsm[i] = 0.f; }
    __syncthreads();
    if (fast) {
        for (int s = 0; s < NSLOT; s++) {
            uint32_t n = cw[s];
            const float* sb_ = bufb + (size_t)s * capw;
            for (uint32_t j = t; j < n; j += 256) {
                float v = sb_[j];
                uint32_t u = fmap(v);
                if (((u >> 9) & (NBA - 1u)) == mid_sel) {
                    uint32_t lb = u & (NBB - 1u);
                    atomicAdd(&cnt[lb], 1u); atomicAdd(&fsm[lb], v);
                }
            }
        }
    } else {
        for (int j = t; j < NPX; j += 256) {
            float tvv = Tp[j];
            if (tvv > 0.f) {
                float v = (which == 0) ? Pp[j] : tvv;
                uint32_t u = fmap(v);
                if ((u >> 20) == pfx1 && ((u >> 9) & (NBA - 1u)) == mid_sel) {
                    uint32_t lb = u & (NBB - 1u);
                    atomicAdd(&cnt[lb], 1u); atomicAdd(&fsm[lb], v);
                }
            }
        }
    }
    __syncthreads();
    {
        uint32_t ms = 0; float mf = 0.f;
        #pragma unroll
        for (int i = 0; i < 2; i++) { ms += cnt[t * 2 + i]; mf += fsm[t * 2 + i]; }
        sc[t] = ms; sfl[t] = mf;
        __syncthreads();
        for (int off = 1; off < 256; off <<= 1) {
            uint32_t a = (t >= off) ? sc[t - off] : 0u;
            float af = (t >= off) ? sfl[t - off] : 0.f;
            __syncthreads();
            sc[t] += a; sfl[t] += af;
            __syncthreads();
        }
        uint32_t incl = sc[t], excl = incl - ms;
        float fx = sfl[t] - mf;
        if (k2 >= excl && k2 < incl) {
            uint32_t c = excl, bin = 0, nk = 0, e = 0; float f = fx;
            for (int i = 0; i < 2; i++) {
                uint32_t hv = cnt[t * 2 + i];
                if (k2 < c + hv) { bin = t * 2 + i; nk = k2 - c; e = hv; break; }
                c += hv; f += fsm[t * 2 + i];
            }
            uint32_t u = (pfx1 << 20) | (mid_sel << 9) | bin;
            ((float*)(ws + SH_OFF))[which * B + b] = funmap(u);
            ws[K_OFF + which * B + b] = nk;      // k3
            ws[EQ_OFF + which * B + b] = e;
            ((float*)(ws + SB_OFF))[which * B + b] += fbelowA + f;
        }
    }
}

// ---------------- params ----------------
__global__ void param_kernel(const float* __restrict__ pred,
                             const float* __restrict__ targ,
                             uint32_t* __restrict__ ws) {
    const int b = threadIdx.x;
    if (b >= B) return;
    const uint32_t n = ws[N_OFF + b];
    const uint32_t k0 = (n - 1u) >> 1;
    float med[2], rs[2];
    uint32_t nab[2];
    #pragma unroll
    for (int w = 0; w < 2; w++) {
        float m = ((const float*)(ws + SH_OFF))[w * B + b];
        uint32_t k3 = ws[K_OFF + w * B + b];
        uint32_t e = ws[EQ_OFF + w * B + b];
        float SBv = ((const float*)(ws + SB_OFF))[w * B + b];
        float ST = ((const float*)(ws + TSUM_OFF))[w * B + b];
        uint32_t CB = k0 - k3;
        uint32_t na = n - CB - e;
        float Sab = ST - SBv - (float)e * m;
        float absdev = (Sab - (float)na * m) + ((float)CB * m - SBv);
        float scale = absdev / (float)n;
        med[w] = m; nab[w] = na;
        rs[w] = 1.f / scale;
        ((float*)(ws + RS_OFF))[w * B + b] = rs[w];
    }
    uint32_t c2 = nab[1];
    ws[C2_OFF + b] = c2;
    uint32_t mi = (uint32_t)NPX - c2 + (uint32_t)TRIM_IDX;
    if (mi > (uint32_t)(NPX - 1)) mi = NPX - 1;
    float p = pred[(size_t)b * NPX + mi];
    float t = targ[(size_t)b * NPX + mi];
    float pn = (p - med[0]) * rs[0], tn = (t - med[1]) * rs[1];
    ((float*)(ws + THR_OFF))[b] = (tn > 0.f) ? fabsf(pn - tn) : 0.f;
}

// ---------------- fused loss: 8-row strip per wave, 2-deep register ring ----------------
__global__ void __launch_bounds__(256) loss_kernel(const float* __restrict__ pred,
                                                   const float* __restrict__ targ,
                                                   uint32_t* __restrict__ ws) {
    const int wid = (blockIdx.x << 2) + (threadIdx.x >> 6);
    const int b = wid / (H / RPW);
    const int s0 = (wid - b * (H / RPW)) * RPW;
    const int l = threadIdx.x & 63;
    const int col = l << 3;
    const float sp = ((const float*)(ws + SH_OFF))[b];
    const float st = ((const float*)(ws + SH_OFF))[B + b];
    const float rp = ((const float*)(ws + RS_OFF))[b];
    const float rt = ((const float*)(ws + RS_OFF))[B + b];
    const float thr = ((const float*)(ws + THR_OFF))[b];
    const float* Pp = pred + (size_t)b * NPX;
    const float* Tp = targ + (size_t)b * NPX;

    const bool g1 = s0 >= 1, g2 = s0 >= 2, g4 = s0 >= 4, g8 = s0 >= 8;
    float rT[2][8], rPN[2][8];
    {
        const int roA = (g1 ? (s0 - 1) : s0) * W + col;
        const int roB = (g2 ? (s0 - 2) : s0) * W + col;
        float4 a0 = *(const float4*)(Tp + roA), a1 = *(const float4*)(Tp + roA + 4);
        float4 b0 = *(const float4*)(Pp + roA), b1 = *(const float4*)(Pp + roA + 4);
        float4 c0 = *(const float4*)(Tp + roB), c1 = *(const float4*)(Tp + roB + 4);
        float4 d0 = *(const float4*)(Pp + roB), d1 = *(const float4*)(Pp + roB + 4);
        float ta[8] = {a0.x,a0.y,a0.z,a0.w,a1.x,a1.y,a1.z,a1.w};
        float pa[8] = {b0.x,b0.y,b0.z,b0.w,b1.x,b1.y,b1.z,b1.w};
        float tc[8] = {c0.x,c0.y,c0.z,c0.w,c1.x,c1.y,c1.z,c1.w};
        float pc[8] = {d0.x,d0.y,d0.z,d0.w,d1.x,d1.y,d1.z,d1.w};
        #pragma unroll
        for (int k = 0; k < 8; k++) {
            rT[1][k] = ta[k]; rPN[1][k] = (pa[k] - sp) * rp;
            rT[0][k] = tc[k]; rPN[0][k] = (pc[k] - sp) * rp;
        }
    }

    float tl = 0.f, gl0 = 0.f, gl1 = 0.f, gl2 = 0.f, gl3 = 0.f;
    uint32_t mc = 0;

    #pragma unroll
    for (int it = 0; it < RPW; ++it) {
        const int ro = (s0 + it) * W + col;
        const int cur = it & 1, prv = cur ^ 1;
        float4 a0 = *(const float4*)(Tp + ro), a1 = *(const float4*)(Tp + ro + 4);
        float4 b0 = *(const float4*)(Pp + ro), b1 = *(const float4*)(Pp + ro + 4);
        float t[8] = {a0.x,a0.y,a0.z,a0.w,a1.x,a1.y,a1.z,a1.w};
        float p[8] = {b0.x,b0.y,b0.z,b0.w,b1.x,b1.y,b1.z,b1.w};
        float t4a = 0.f, t4b = 0.f, p4a = 0.f, p4b = 0.f, t8a = 0.f, p8a = 0.f;
        if (it == 0) {
            const int ro4 = g4 ? ro - 4 * W : ro;
            t4a = Tp[ro4]; t4b = Tp[ro4 + 4]; p4a = Pp[ro4]; p4b = Pp[ro4 + 4];
            const int ro8 = g8 ? ro - 8 * W : ro;
            t8a = Tp[ro8]; p8a = Pp[ro8];
        }
        if (it == 4) {
            const int ro4 = ro - 4 * W;
            t4a = Tp[ro4]; t4b = Tp[ro4 + 4]; p4a = Pp[ro4]; p4b = Pp[ro4 + 4];
        }
        float pn[8]; bool m[8];
        #pragma unroll
        for (int k = 0; k < 8; k++) { pn[k] = (p[k] - sp) * rp; m[k] = t[k] > st; }

        #pragma unroll
        for (int k = 0; k < 8; k++) {
            if (m[k]) {
                float tn = (t[k] - st) * rt;
                float r = fabsf(pn[k] - tn);
                if (r <= thr) tl += r;
            }
        }
        float t7p = __shfl_up(t[7], 1), pn7p = __shfl_up(pn[7], 1);
        if (l > 0 && m[0] && t7p > st) gl0 += fabsf(pn[0] - pn7p);
        #pragma unroll
        for (int k = 1; k < 8; k++) if (m[k] && m[k - 1]) gl0 += fabsf(pn[k] - pn[k - 1]);
        if (it > 0 || g1) {
            #pragma unroll
            for (int k = 0; k < 8; k++)
                if (m[k] && rT[prv][k] > st) gl0 += fabsf(pn[k] - rPN[prv][k]);
        }
        if ((it & 1) == 0) {
            float t6p = __shfl_up(t[6], 1), pn6p = __shfl_up(pn[6], 1);
            mc += (uint32_t)m[0] + m[2] + m[4] + m[6];
            if (l > 0 && m[0] && t6p > st) gl1 += fabsf(pn[0] - pn6p);
            if (m[2] && m[0]) gl1 += fabsf(pn[2] - pn[0]);
            if (m[4] && m[2]) gl1 += fabsf(pn[4] - pn[2]);
            if (m[6] && m[4]) gl1 += fabsf(pn[6] - pn[4]);
            if (it >= 2 || g2) {
                if (m[0] && rT[cur][0] > st) gl1 += fabsf(pn[0] - rPN[cur][0]);
                if (m[2] && rT[cur][2] > st) gl1 += fabsf(pn[2] - rPN[cur][2]);
                if (m[4] && rT[cur][4] > st) gl1 += fabsf(pn[4] - rPN[cur][4]);
                if (m[6] && rT[cur][6] > st) gl1 += fabsf(pn[6] - rPN[cur][6]);
            }
            if ((it & 3) == 0) {
                float t4p = __shfl_up(t[4], 1), pn4p = __shfl_up(pn[4], 1);
                mc += ((uint32_t)m[0] + m[4]) << 11;
                if (l > 0 && m[0] && t4p > st) gl2 += fabsf(pn[0] - pn4p);
                if (m[4] && m[0]) gl2 += fabsf(pn[4] - pn[0]);
                if (it == 4 || g4) {
                    if (m[0] && t4a > st) gl2 += fabsf(pn[0] - (p4a - sp) * rp);
                    if (m[4] && t4b > st) gl2 += fabsf(pn[4] - (p4b - sp) * rp);
                }
                if (it == 0) {
                    float t0p = __shfl_up(t[0], 1), pn0p = __shfl_up(pn[0], 1);
                    mc += ((uint32_t)m[0]) << 22;
                    if (l > 0 && m[0] && t0p > st) gl3 += fabsf(pn[0] - pn0p);
                    if (g8 && m[0] && t8a > st) gl3 += fabsf(pn[0] - (p8a - sp) * rp);
                }
            }
        }
        #pragma unroll
        for (int k = 0; k < 8; k++) { rT[cur][k] = t[k]; rPN[cur][k] = pn[k]; }
    }

    for (int off = 32; off; off >>= 1) {
        tl  += __shfl_down(tl, off, 64);
        gl0 += __shfl_down(gl0, off, 64);
        gl1 += __shfl_down(gl1, off, 64);
        gl2 += __shfl_down(gl2, off, 64);
        gl3 += __shfl_down(gl3, off, 64);
        mc  += __shfl_down(mc, off, 64);
    }
    if (l == 0) {
        float* gs = (float*)(ws + GS_OFF);
        atomicAdd(((float*)(ws + TS_OFF)) + b, tl);
        atomicAdd(gs + b, gl0);
        atomicAdd(gs + B + b, gl1);
        atomicAdd(gs + 2 * B + b, gl2);
        atomicAdd(gs + 3 * B + b, gl3);
        atomicAdd(ws + MS_OFF + b, mc & 0x7FFu);
        atomicAdd(ws + MS_OFF + B + b, (mc >> 11) & 0x7FFu);
        atomicAdd(ws + MS_OFF + 2 * B + b, mc >> 22);
    }
}

// ---------------- finalize ----------------
__global__ void finalize_kernel(const uint32_t* __restrict__ ws, float* __restrict__ out) {
    const int b = threadIdx.x;
    float v = 0.f;
    if (b < B) {
        float c2 = (float)ws[C2_OFF + b];
        const float* tsum = (const float*)(ws + TS_OFF);
        const float* gsum = (const float*)(ws + GS_OFF);
        float tm = (c2 > 0.f) ? tsum[b] / (2.f * c2) : 0.f;
        float g = (c2 > 0.f) ? gsum[b] / c2 : 0.f;
        for (int z = 0; z < 3; z++) {
            float ms = (float)ws[MS_OFF + z * B + b];
            g += (ms > 0.f) ? gsum[(1 + z) * B + b] / ms : 0.f;
        }
        v = tm + 0.5f * g;
    }
    for (int off = 32; off; off >>= 1) v += __shfl_down(v, off, 64);
    if (b == 0) out[0] = v * (1.f / 64.f);
}

extern "C" void kernel_launch(void* const* d_in, const int* in_sizes, int n_in,
                              void* d_out, int out_size, void* d_ws, size_t ws_size,
                              hipStream_t stream) {
    const float* pred = (const float*)d_in[0];
    const float* targ = (const float*)d_in[1];
    float* out = (float*)d_out;
    uint32_t* ws = (uint32_t*)d_ws;

    long avail = (long)(ws_size / 4) - (long)FIX_U32;
    int capw = 0;
    if (avail > 0) {
        long c = avail / (2L * B * NSLOT);
        capw = (int)(c < CAPW ? c : CAPW);
    }

    hipMemsetAsync(ws, 0, (size_t)ZERO_U32 * 4, stream);

    hist1_kernel<<<dim3(16, B), 256, 0, stream>>>(pred, targ, ws);
    select1_kernel<<<dim3(B, 2), 256, 0, stream>>>(ws);
    collect2_kernel<<<dim3(16, B), 256, 0, stream>>>(pred, targ, ws, capw);
    small3_kernel<<<dim3(B, 2), 256, 0, stream>>>(pred, targ, ws, capw);
    param_kernel<<<1, 64, 0, stream>>>(pred, targ, ws);
    loss_kernel<<<dim3(B * (H / RPW) / 4), 256, 0, stream>>>(pred, targ, ws);
    finalize_kernel<<<1, 64, 0, stream>>>(ws, out);
}